// Round 3
// baseline (131.942 us; speedup 1.0000x reference)
//
#include <hip/hip_runtime.h>
#include <math.h>

// RBF kernel matrix: cov[i][j] = exp(lv - 0.5*||(x_i - xx_j) * inv_scale||^2)
// Log2-domain expansion (v_exp_f32 = exp2 applied directly):
//   W[d]   = inv_scale[d]^2 * log2(e)
//   B[j,d] = xx[j,d] * W[d]
//   c[j]   = lv*log2e - 0.5 * sum_d xx[j,d]^2 * W[d]
//   h_i    = -0.5 * sum_d x[i,d]^2 * W[d]
//   cov    = exp2(h_i + c_j + sum_d x[i,d] * B[j,d])
//
// R3: maximally fill-like store stream. One row per block, one float4 per
// thread, grid (4, 4096) = 65536 waves. Block-linear order sweeps the output
// sequentially in 4 KB chunks — the exact address pattern of the 5.9 TB/s
// harness fill. Discriminates "kernel store-walled at 1.5 TB/s" vs "kernel
// small, dur_us dominated by harness fill (~45 us) + fixed graph cost".

constexpr int D   = 8;   // feature dim (fixed by reference)
constexpr int TJ  = 4;   // columns per thread -> one float4 store
constexpr int BLK = 256; // threads per block (4 waves)

typedef float f32x4 __attribute__((ext_vector_type(4)));

__global__ __launch_bounds__(BLK) void rbf_kernel(
    const float* __restrict__ x,         // [N, D]
    const float* __restrict__ xx,        // [M, D]
    const float* __restrict__ log_scale, // [D]
    const float* __restrict__ log_var,   // [1]
    float* __restrict__ out,             // [N, M]
    int N, int M)
{
    const int j0 = blockIdx.x * (BLK * TJ) + threadIdx.x * TJ;
    const int i  = blockIdx.y;
    if (j0 + TJ > M || i >= N) return;

    constexpr float LOG2E = 1.4426950408889634f;
    float w[D];
#pragma unroll
    for (int d = 0; d < D; ++d) {
        const float s = __expf(-log_scale[d]);  // 1/scale
        w[d] = s * s * LOG2E;
    }
    const float lv2 = log_var[0] * LOG2E;

    // Row term h_i (wave-uniform x row -> broadcast L2-hot load)
    const float4* px = (const float4*)(x + (size_t)i * D);
    const float4 xa = px[0], xb = px[1];
    const float xv[D] = {xa.x, xa.y, xa.z, xa.w, xb.x, xb.y, xb.z, xb.w};
    float hq = 0.f;
#pragma unroll
    for (int d = 0; d < D; ++d) hq = fmaf(xv[d] * w[d], xv[d], hq);
    const float h = -0.5f * hq;

    // Per-column: exponent = h + c_j + sum_d x[d]*B[j,d]
    float res[TJ];
#pragma unroll
    for (int jj = 0; jj < TJ; ++jj) {
        const float4* p = (const float4*)(xx + (size_t)(j0 + jj) * D);
        const float4 a = p[0], b = p[1];
        const float v[D] = {a.x, a.y, a.z, a.w, b.x, b.y, b.z, b.w};
        float e = h + lv2;
        float q = 0.f;
#pragma unroll
        for (int d = 0; d < D; ++d) {
            const float bd = v[d] * w[d];
            q = fmaf(v[d], bd, q);      // xx^2 * W accum
            e = fmaf(xv[d], bd, e);     // x · B accum
        }
        res[jj] = __builtin_amdgcn_exp2f(fmaf(-0.5f, q, e));
    }

    const f32x4 o = {res[0], res[1], res[2], res[3]};
    *(f32x4*)(out + (size_t)i * M + j0) = o;
}

extern "C" void kernel_launch(void* const* d_in, const int* in_sizes, int n_in,
                              void* d_out, int out_size, void* d_ws, size_t ws_size,
                              hipStream_t stream) {
    const float* x  = (const float*)d_in[0];
    const float* xx = (const float*)d_in[1];
    const float* ls = (const float*)d_in[2];
    const float* lv = (const float*)d_in[3];
    float* out      = (float*)d_out;

    const int N = in_sizes[0] / D;
    const int M = in_sizes[1] / D;

    dim3 block(BLK, 1, 1);
    dim3 grid((M + BLK * TJ - 1) / (BLK * TJ), N, 1);
    rbf_kernel<<<grid, block, 0, stream>>>(x, xx, ls, lv, out, N, M);
}

// Round 4
// 86.659 us; speedup vs baseline: 1.5225x; 1.5225x over previous
//
#include <hip/hip_runtime.h>
#include <math.h>

// RBF kernel matrix: cov[i][j] = exp(lv - 0.5*||(x_i - xx_j) * inv_scale||^2)
// Log2-domain expansion (v_exp_f32 = exp2 applied directly):
//   W[d]   = inv_scale[d]^2 * log2(e)
//   B[j,d] = xx[j,d] * W[d]
//   c[j]   = lv*log2e - 0.5 * sum_d xx[j,d]^2 * W[d]
//   h_i    = -0.5 * sum_d x[i,d]^2 * W[d]
//   cov    = exp2(h_i + c_j + sum_d x[i,d] * B[j,d])
//
// Calibrated: dur_us = kernel + ~65.5us fixed graph overhead (45us fill + misc).
// Baseline kernel ~20.5us = 3.3 TB/s writes; fill proves 5.9 TB/s on this box
// -> write roofline 11.4us. R4: persistent-column blocks (precompute B,c once
// per block, reuse over 16 rows) + batched back-to-back stores (compute 8 rows
// into regs, then burst 8x 1KB wave-stores) to decouple store issue from the
// dependent FMA/exp chain.

constexpr int D    = 8;   // feature dim (fixed by reference)
constexpr int TJ   = 4;   // columns per thread -> one float4 store
constexpr int BLK  = 256; // threads per block
constexpr int RPB  = 16;  // rows per block
constexpr int RBAT = 8;   // rows per store batch (res[] registers)

typedef float f32x4 __attribute__((ext_vector_type(4)));

__global__ __launch_bounds__(BLK) void rbf_kernel(
    const float* __restrict__ x,         // [N, D]
    const float* __restrict__ xx,        // [M, D]
    const float* __restrict__ log_scale, // [D]
    const float* __restrict__ log_var,   // [1]
    float* __restrict__ out,             // [N, M]
    int N, int M)
{
    const int j0 = blockIdx.x * (BLK * TJ) + threadIdx.x * TJ;
    const int i0 = blockIdx.y * RPB;
    if (j0 + TJ > M || i0 + RPB > N) return;  // exact for 4096; safety only

    constexpr float LOG2E = 1.4426950408889634f;
    float w[D];
#pragma unroll
    for (int d = 0; d < D; ++d) {
        const float s = __expf(-log_scale[d]);  // 1/scale
        w[d] = s * s * LOG2E;                   // log2e folded in
    }
    const float lv2 = log_var[0] * LOG2E;

    // Persistent per-column state for this block's 1024-col span:
    // B[jj][d] = xx*W, c[jj] = lv2 - 0.5*sum(xx^2*W). Reused for all RPB rows.
    float B[TJ][D], c[TJ];
#pragma unroll
    for (int jj = 0; jj < TJ; ++jj) {
        const float4* p = (const float4*)(xx + (size_t)(j0 + jj) * D);
        const float4 a = p[0], b = p[1];
        const float v[D] = {a.x, a.y, a.z, a.w, b.x, b.y, b.z, b.w};
        float q = 0.f;
#pragma unroll
        for (int d = 0; d < D; ++d) {
            B[jj][d] = v[d] * w[d];
            q = fmaf(v[d], B[jj][d], q);
        }
        c[jj] = fmaf(-0.5f, q, lv2);
    }

#pragma unroll
    for (int bat = 0; bat < RPB / RBAT; ++bat) {
        const int ib = i0 + bat * RBAT;
        float res[RBAT][TJ];

        // Compute RBAT rows fully into registers (no stores interleaved).
#pragma unroll
        for (int r = 0; r < RBAT; ++r) {
            const int i = ib + r;
            // Wave-uniform x-row address -> broadcast, L1/L2-hot.
            const float4* px = (const float4*)(x + (size_t)i * D);
            const float4 a = px[0], b = px[1];
            const float xv[D] = {a.x, a.y, a.z, a.w, b.x, b.y, b.z, b.w};
            float q = 0.f;
#pragma unroll
            for (int d = 0; d < D; ++d) q = fmaf(xv[d] * w[d], xv[d], q);
            const float h = -0.5f * q;
#pragma unroll
            for (int jj = 0; jj < TJ; ++jj) {
                float e = h + c[jj];
#pragma unroll
                for (int d = 0; d < D; ++d) e = fmaf(xv[d], B[jj][d], e);
                res[r][jj] = __builtin_amdgcn_exp2f(e);
            }
        }

        // Burst the batch: RBAT back-to-back 1KB wave-stores (fill-like).
#pragma unroll
        for (int r = 0; r < RBAT; ++r) {
            const f32x4 o = {res[r][0], res[r][1], res[r][2], res[r][3]};
            *(f32x4*)(out + (size_t)(ib + r) * M + j0) = o;
        }
    }
}

extern "C" void kernel_launch(void* const* d_in, const int* in_sizes, int n_in,
                              void* d_out, int out_size, void* d_ws, size_t ws_size,
                              hipStream_t stream) {
    const float* x  = (const float*)d_in[0];
    const float* xx = (const float*)d_in[1];
    const float* ls = (const float*)d_in[2];
    const float* lv = (const float*)d_in[3];
    float* out      = (float*)d_out;

    const int N = in_sizes[0] / D;
    const int M = in_sizes[1] / D;

    dim3 block(BLK, 1, 1);
    dim3 grid((M + BLK * TJ - 1) / (BLK * TJ), (N + RPB - 1) / RPB, 1);
    rbf_kernel<<<grid, block, 0, stream>>>(x, xx, ls, lv, out, N, M);
}